// Round 14
// baseline (1093.553 us; speedup 1.0000x reference)
//
#include <hip/hip_runtime.h>
#include <cstddef>

#define L 16
#define PLANE 256
#define VOL 65536

typedef __attribute__((ext_vector_type(8))) short short8;
typedef __attribute__((ext_vector_type(8))) _Float16 half8;
typedef __attribute__((ext_vector_type(4))) float f32x4;
typedef __attribute__((ext_vector_type(4))) int i32x4;
typedef unsigned int u32;
typedef unsigned short u16;

__device__ __forceinline__ u16 f2h_bits(float f) {
    _Float16 h = (_Float16)f;             // RTN
    return __builtin_bit_cast(u16, h);
}

// DPP lane-shift within 16-lane rows; bound_ctrl + old=0 -> zero fill at row
// edges == SAME-padding for the d4 dimension, for free.
template <int CTRL>
__device__ __forceinline__ int dppmov(int v) {
    return __builtin_amdgcn_update_dpp(0, v, CTRL, 0xf, 0xf, true);
}
template <int CTRL>
__device__ __forceinline__ half8 dpp8(half8 v) {
    i32x4 u = __builtin_bit_cast(i32x4, v), r;
    r[0] = dppmov<CTRL>(u[0]); r[1] = dppmov<CTRL>(u[1]);
    r[2] = dppmov<CTRL>(u[2]); r[3] = dppmov<CTRL>(u[3]);
    return __builtin_bit_cast(half8, r);
}

// ---------------------------------------------------------------------------
// Pack layer0 (IC=2) weights to fp32 [i][tap][o].
// ---------------------------------------------------------------------------
__global__ void pack_w0(const float* __restrict__ k0, float* __restrict__ dst)
{
    int idx = blockIdx.x * 256 + threadIdx.x;   // (i*81 + t)*32 + o
    if (idx >= 2 * 81 * 32) return;
    int o = idx & 31;
    int t = (idx >> 5) % 81;
    int i = idx / (32 * 81);
    dst[idx] = k0[(size_t)(o * 2 + i) * 81 + t];
}

// ---------------------------------------------------------------------------
// Pack k1..k4 to SINGLE fp16: wpk[layer][tap][o][i], 81*1024 u16 per layer.
// (R11: fp16 RTN on hidden weights moved absmax by exactly zero.)
// ---------------------------------------------------------------------------
__global__ void pack_h1(const float* __restrict__ k1, const float* __restrict__ k2,
                        const float* __restrict__ k3, const float* __restrict__ k4,
                        u16* __restrict__ dst)
{
    int idx = blockIdx.x * 256 + threadIdx.x;
    if (idx >= 4 * 81 * 1024) return;
    int layer = idx / (81 * 1024);
    int r = idx % (81 * 1024);
    int t = r / 1024;
    int oi = r % 1024;                  // o*32 + i
    int o = oi >> 5, i = oi & 31;
    const float* src = layer == 0 ? k1 : layer == 1 ? k2 : layer == 2 ? k3 : k4;
    float w = src[(size_t)(o * 32 + i) * 81 + t];
    dst[((size_t)layer * 81 + t) * 1024 + oi] = f2h_bits(w);
}

// ---------------------------------------------------------------------------
// Pack k5 (OC=2) to fp16 padded to 16: wp5[tap][n=16][k=32], 81*512 u16.
// ---------------------------------------------------------------------------
__global__ void pack_k5(const float* __restrict__ k5, u16* __restrict__ dst)
{
    int idx = blockIdx.x * 256 + threadIdx.x;   // t*512 + o*32 + i
    if (idx >= 81 * 512) return;
    int t = idx >> 9;
    int oi = idx & 511;
    int o = oi >> 5, i = oi & 31;
    float w = (o < 2) ? k5[(size_t)(o * 32 + i) * 81 + t] : 0.0f;
    dst[idx] = f2h_bits(w);
}

// ---------------------------------------------------------------------------
// MFMA conv layer, IC=OC=32, PReLU. fp16 SINGLE-pass, NO LDS, NO barriers.
// Activations [n][d1][d2][pos=d3*16+d4][ch]. R14: lb(256,6) — natural VGPR
// demand is 56 (« the 85 cap), so no spill; raises resident waves/SIMD to
// cover A-load latency with TLP. (R7's spill was at demand ~112 — n/a here.)
// ---------------------------------------------------------------------------
__global__ __launch_bounds__(256, 6)
void conv4d_mfma(const u16* __restrict__ xh, const u16* __restrict__ wl_,
                 const float* __restrict__ slopes, int sidx, u16* __restrict__ yh)
{
    const int blk = blockIdx.x;
    // XCD swizzle: xcd = blk&7 owns d1 rows {2*xcd, 2*xcd+1}, n-major order.
    const int xcd = blk & 7;
    const int s = blk >> 3;
    const int n = s >> 5;
    const int t_ = s & 31;
    const int d1 = xcd * 2 + (t_ >> 4);
    const int d2 = t_ & 15;

    const int lane = threadIdx.x & 63, wv = threadIdx.x >> 6;
    const int l15 = lane & 15, q = lane >> 4;

    f32x4 acc[4][2];
#pragma unroll
    for (int f = 0; f < 4; ++f)
#pragma unroll
        for (int nf = 0; nf < 2; ++nf)
            acc[f][nf] = (f32x4){0.f, 0.f, 0.f, 0.f};

    const size_t nbase = (size_t)n * 256 * 8192;
    const int aoff = l15 * 32 + q * 8;       // within-plane frag offset (dd=1)
    const half8 zero8 = (half8)(_Float16)0;

#pragma unroll 1
    for (int da = 0; da < 3; ++da) {
        const int a = d1 + da - 1;
        if ((unsigned)a > 15u) continue;     // block-uniform: pad plane = 0
#pragma unroll 1
        for (int db = 0; db < 3; ++db) {
            const int b = d2 + db - 1;
            if ((unsigned)b > 15u) continue;
            const u16* Hp = xh + nbase + (size_t)(a * 16 + b) * 8192;
            const u16* wt0 = wl_ + (size_t)((da * 3 + db) * 9) * 1024;

            // base A-frags (dd=1, col=l15): rows wv*4-1 .. wv*4+4
            half8 ax[6];
#pragma unroll
            for (int r6 = 0; r6 < 6; ++r6) {
                const int d3c = (wv * 4 + r6 - 1) & 15;   // wrap; edges zeroed
                ax[r6] = *(const half8*)(Hp + d3c * 512 + aoff);
            }
            if (wv == 0)      ax[0] = zero8;  // d3 = -1 pad row
            else if (wv == 3) ax[5] = zero8;  // d3 = 16 pad row

            // ---- dd outer: shift A once, 3 dc taps reuse it ----
#pragma unroll
            for (int dd = 0; dd < 3; ++dd) {
                half8 As[6];
#pragma unroll
                for (int r6 = 0; r6 < 6; ++r6) {
                    if (dd == 0)      As[r6] = dpp8<0x111>(ax[r6]); // col-1
                    else if (dd == 1) As[r6] = ax[r6];
                    else              As[r6] = dpp8<0x101>(ax[r6]); // col+1
                }
#pragma unroll
                for (int dc = 0; dc < 3; ++dc) {
                    const u16* wb = wt0 + (dc * 3 + dd) * 1024;
                    half8 B0 = *(const half8*)(wb + aoff);
                    half8 B1 = *(const half8*)(wb + 512 + aoff);
#pragma unroll
                    for (int f = 0; f < 4; ++f) {
                        acc[f][0] = __builtin_amdgcn_mfma_f32_16x16x32_f16(As[f + dc], B0, acc[f][0], 0, 0, 0);
                        acc[f][1] = __builtin_amdgcn_mfma_f32_16x16x32_f16(As[f + dc], B1, acc[f][1], 0, 0, 0);
                    }
                }
            }
        }
    }

    // ---- epilogue: PReLU, fp16 pack, store to [pos][ch] buffer ----
    const float slope = slopes[sidx];
    u16* Hb = yh + ((size_t)(n * 256) + d1 * 16 + d2) * 8192;
#pragma unroll
    for (int f = 0; f < 4; ++f) {
#pragma unroll
        for (int nf = 0; nf < 2; ++nf) {
            const int o = nf * 16 + l15;
#pragma unroll
            for (int j = 0; j < 4; ++j) {
                float v = acc[f][nf][j];
                v = v >= 0.f ? v : slope * v;
                const int pos = (wv * 4 + f) * 16 + q * 4 + j;
                Hb[pos * 32 + o] = f2h_bits(v);
            }
        }
    }
}

// ---------------------------------------------------------------------------
// Layer 0: IC=2, fp32 math, PReLU; original x layout in, fp16 out.
// ---------------------------------------------------------------------------
__global__ __launch_bounds__(256, 4)
void conv4d_c2(const float* __restrict__ x, const float* __restrict__ wp,
               const float* __restrict__ slopes, u16* __restrict__ yh)
{
    const int blk = blockIdx.x;
    const int d2 = blk & 15, d1 = (blk >> 4) & 15, n = blk >> 8;
    const int tid = threadIdx.x;
    const int c = tid >> 4, d = tid & 15;

    __shared__ float xs[3][3][18][18];
    float* xsf = &xs[0][0][0][0];
    for (int idx = tid; idx < 3 * 3 * 18 * 18; idx += 256) xsf[idx] = 0.0f;

    float acc[32];
#pragma unroll
    for (int o = 0; o < 32; ++o) acc[o] = 0.0f;

    for (int i = 0; i < 2; ++i) {
#pragma unroll
        for (int da = 0; da < 3; ++da) {
            const int a = d1 + da - 1;
#pragma unroll
            for (int db = 0; db < 3; ++db) {
                const int b = d2 + db - 1;
                float v = 0.0f;
                if (a >= 0 && a < L && b >= 0 && b < L)
                    v = x[(((size_t)(n * 2 + i) * L + a) * L + b) * PLANE + c * L + d];
                xs[da][db][c + 1][d + 1] = v;
            }
        }
        __syncthreads();

        const float* wpi = wp + (size_t)i * 81 * 32;
#pragma unroll 1
        for (int da = 0; da < 3; ++da) {
#pragma unroll 1
            for (int db = 0; db < 3; ++db) {
                float xv[3][3];
#pragma unroll
                for (int dc = 0; dc < 3; ++dc)
#pragma unroll
                    for (int dd = 0; dd < 3; ++dd)
                        xv[dc][dd] = xs[da][db][c + dc][d + dd];

                const float* wt = wpi + (da * 3 + db) * 9 * 32;
#pragma unroll
                for (int dc = 0; dc < 3; ++dc) {
#pragma unroll
                    for (int dd = 0; dd < 3; ++dd) {
                        const float* wr = wt + (dc * 3 + dd) * 32;
#pragma unroll
                        for (int o = 0; o < 32; ++o)
                            acc[o] = fmaf(xv[dc][dd], wr[o], acc[o]);
                    }
                }
            }
        }
        __syncthreads();
    }

    const float slope = slopes[0];
    u16* Hb = yh + ((size_t)(n * 256) + d1 * 16 + d2) * 8192 + (size_t)tid * 32;
    short8 hs[4];
#pragma unroll
    for (int k = 0; k < 4; ++k)
#pragma unroll
        for (int j = 0; j < 8; ++j) {
            float v = acc[k * 8 + j];
            v = v >= 0.f ? v : slope * v;
            hs[k][j] = (short)f2h_bits(v);
        }
#pragma unroll
    for (int k = 0; k < 4; ++k)
        *(short8*)(Hb + k * 8) = hs[k];
}

// ---------------------------------------------------------------------------
// Final layer: IC=32, OC=2 (padded to 16), no PReLU. MFMA, NO LDS/barriers.
// lb(256,6): natural demand ~52 VGPR, cap 85 — no spill.
// ---------------------------------------------------------------------------
__global__ __launch_bounds__(256, 6)
void conv4d_out(const u16* __restrict__ xh, const u16* __restrict__ w5,
                float* __restrict__ out)
{
    const int blk = blockIdx.x;
    const int xcd = blk & 7;      // same swizzle as hidden layers (L2 locality)
    const int s = blk >> 3;
    const int n = s >> 5;
    const int t_ = s & 31;
    const int d1 = xcd * 2 + (t_ >> 4);
    const int d2 = t_ & 15;

    const int lane = threadIdx.x & 63, wv = threadIdx.x >> 6;
    const int l15 = lane & 15, q = lane >> 4;

    f32x4 acc[4];
#pragma unroll
    for (int f = 0; f < 4; ++f) acc[f] = (f32x4){0.f, 0.f, 0.f, 0.f};

    const size_t nbase = (size_t)n * 256 * 8192;
    const int aoff = l15 * 32 + q * 8;
    const half8 zero8 = (half8)(_Float16)0;
    const int boff = l15 * 32 + q * 8;    // B[n=l15][k=q*8..], 512 u16/tap

#pragma unroll 1
    for (int da = 0; da < 3; ++da) {
        const int a = d1 + da - 1;
        if ((unsigned)a > 15u) continue;
#pragma unroll 1
        for (int db = 0; db < 3; ++db) {
            const int b = d2 + db - 1;
            if ((unsigned)b > 15u) continue;
            const u16* Hp = xh + nbase + (size_t)(a * 16 + b) * 8192;
            const u16* wt0 = w5 + (size_t)((da * 3 + db) * 9) * 512;

            half8 ax[6];
#pragma unroll
            for (int r6 = 0; r6 < 6; ++r6) {
                const int d3c = (wv * 4 + r6 - 1) & 15;
                ax[r6] = *(const half8*)(Hp + d3c * 512 + aoff);
            }
            if (wv == 0)      ax[0] = zero8;
            else if (wv == 3) ax[5] = zero8;

#pragma unroll
            for (int dd = 0; dd < 3; ++dd) {
                half8 As[6];
#pragma unroll
                for (int r6 = 0; r6 < 6; ++r6) {
                    if (dd == 0)      As[r6] = dpp8<0x111>(ax[r6]);
                    else if (dd == 1) As[r6] = ax[r6];
                    else              As[r6] = dpp8<0x101>(ax[r6]);
                }
#pragma unroll
                for (int dc = 0; dc < 3; ++dc) {
                    const u16* wb = wt0 + (dc * 3 + dd) * 512;
                    half8 B0 = *(const half8*)(wb + boff);
#pragma unroll
                    for (int f = 0; f < 4; ++f)
                        acc[f] = __builtin_amdgcn_mfma_f32_16x16x32_f16(As[f + dc], B0, acc[f], 0, 0, 0);
                }
            }
        }
    }

    // ---- epilogue: lanes l15<2 hold valid oc; D row = d4 = q*4+j ----
    if (l15 < 2) {
        float* ob = out + (size_t)(n * 2 + l15) * VOL + (size_t)(d1 * 16 + d2) * 256;
#pragma unroll
        for (int f = 0; f < 4; ++f) {
            const int d3 = wv * 4 + f;
            *(f32x4*)(ob + d3 * 16 + q * 4) = acc[f];
        }
    }
}

extern "C" void kernel_launch(void* const* d_in, const int* in_sizes, int n_in,
                              void* d_out, int out_size, void* d_ws, size_t ws_size,
                              hipStream_t stream)
{
    (void)in_sizes; (void)n_in; (void)out_size; (void)ws_size;
    const float* x      = (const float*)d_in[0];
    const float* k0     = (const float*)d_in[1];
    const float* k1     = (const float*)d_in[2];
    const float* k2     = (const float*)d_in[3];
    const float* k3     = (const float*)d_in[4];
    const float* k4     = (const float*)d_in[5];
    const float* k5     = (const float*)d_in[6];
    const float* slopes = (const float*)d_in[7];
    float* outp = (float*)d_out;

    // fp16 activation ping-pong buffers in d_ws: 33.5 MB each; wp5 after.
    u16* b0 = (u16*)d_ws;
    u16* b1 = b0 + (size_t)2048 * 8192;
    u16* wp5 = b1 + (size_t)2048 * 8192;    // 81*512 u16 = 83 KB

    // Hidden/layer0 weights in d_out (consumed before conv4d_out writes it):
    u16* wpk = (u16*)d_out;                 // 4*81*1024 u16 = 663 KB
    float* wp0 = outp + 165888;             // 5184 fp32 after that

    pack_h1<<<dim3(1296), 256, 0, stream>>>(k1, k2, k3, k4, wpk);
    pack_w0<<<dim3(21), 256, 0, stream>>>(k0, wp0);
    pack_k5<<<dim3(162), 256, 0, stream>>>(k5, wp5);

    const dim3 grid(8 * L * L);
    const dim3 block(256);

    conv4d_c2<<<grid, block, 0, stream>>>(x, wp0, slopes, b0);
    conv4d_mfma<<<grid, block, 0, stream>>>(b0, wpk + (size_t)0 * 81 * 1024, slopes, 1, b1);
    conv4d_mfma<<<grid, block, 0, stream>>>(b1, wpk + (size_t)1 * 81 * 1024, slopes, 2, b0);
    conv4d_mfma<<<grid, block, 0, stream>>>(b0, wpk + (size_t)2 * 81 * 1024, slopes, 3, b1);
    conv4d_mfma<<<grid, block, 0, stream>>>(b1, wpk + (size_t)3 * 81 * 1024, slopes, 4, b0);
    conv4d_out<<<grid, block, 0, stream>>>(b0, wp5, outp);
}

// Round 15
// 744.843 us; speedup vs baseline: 1.4682x; 1.4682x over previous
//
#include <hip/hip_runtime.h>
#include <cstddef>

#define L 16
#define PLANE 256
#define VOL 65536

typedef __attribute__((ext_vector_type(8))) short short8;
typedef __attribute__((ext_vector_type(8))) _Float16 half8;
typedef __attribute__((ext_vector_type(4))) float f32x4;
typedef __attribute__((ext_vector_type(4))) int i32x4;
typedef unsigned int u32;
typedef unsigned short u16;

__device__ __forceinline__ u16 f2h_bits(float f) {
    _Float16 h = (_Float16)f;             // RTN
    return __builtin_bit_cast(u16, h);
}

// DPP lane-shift within 16-lane rows; bound_ctrl + old=0 -> zero fill at row
// edges == SAME-padding for the d4 dimension, for free.
template <int CTRL>
__device__ __forceinline__ int dppmov(int v) {
    return __builtin_amdgcn_update_dpp(0, v, CTRL, 0xf, 0xf, true);
}
template <int CTRL>
__device__ __forceinline__ half8 dpp8(half8 v) {
    i32x4 u = __builtin_bit_cast(i32x4, v), r;
    r[0] = dppmov<CTRL>(u[0]); r[1] = dppmov<CTRL>(u[1]);
    r[2] = dppmov<CTRL>(u[2]); r[3] = dppmov<CTRL>(u[3]);
    return __builtin_bit_cast(half8, r);
}

// ---------------------------------------------------------------------------
// Pack layer0 (IC=2) weights to fp32 [i][tap][o].
// ---------------------------------------------------------------------------
__global__ void pack_w0(const float* __restrict__ k0, float* __restrict__ dst)
{
    int idx = blockIdx.x * 256 + threadIdx.x;   // (i*81 + t)*32 + o
    if (idx >= 2 * 81 * 32) return;
    int o = idx & 31;
    int t = (idx >> 5) % 81;
    int i = idx / (32 * 81);
    dst[idx] = k0[(size_t)(o * 2 + i) * 81 + t];
}

// ---------------------------------------------------------------------------
// Pack k1..k4 to SINGLE fp16: wpk[layer][tap][o][i], 81*1024 u16 per layer.
// (R11: fp16 RTN on hidden weights moved absmax by exactly zero.)
// ---------------------------------------------------------------------------
__global__ void pack_h1(const float* __restrict__ k1, const float* __restrict__ k2,
                        const float* __restrict__ k3, const float* __restrict__ k4,
                        u16* __restrict__ dst)
{
    int idx = blockIdx.x * 256 + threadIdx.x;
    if (idx >= 4 * 81 * 1024) return;
    int layer = idx / (81 * 1024);
    int r = idx % (81 * 1024);
    int t = r / 1024;
    int oi = r % 1024;                  // o*32 + i
    int o = oi >> 5, i = oi & 31;
    const float* src = layer == 0 ? k1 : layer == 1 ? k2 : layer == 2 ? k3 : k4;
    float w = src[(size_t)(o * 32 + i) * 81 + t];
    dst[((size_t)layer * 81 + t) * 1024 + oi] = f2h_bits(w);
}

// ---------------------------------------------------------------------------
// Pack k5 (OC=2) to fp16 padded to 16: wp5[tap][n=16][k=32], 81*512 u16.
// ---------------------------------------------------------------------------
__global__ void pack_k5(const float* __restrict__ k5, u16* __restrict__ dst)
{
    int idx = blockIdx.x * 256 + threadIdx.x;   // t*512 + o*32 + i
    if (idx >= 81 * 512) return;
    int t = idx >> 9;
    int oi = idx & 511;
    int o = oi >> 5, i = oi & 31;
    float w = (o < 2) ? k5[(size_t)(o * 32 + i) * 81 + t] : 0.0f;
    dst[idx] = f2h_bits(w);
}

// ---------------------------------------------------------------------------
// MFMA conv layer, IC=OC=32, PReLU. fp16 SINGLE-pass, NO LDS, NO barriers.
// Activations [n][d1][d2][pos=d3*16+d4][ch].
// lb(256,5): unified cap 512/5=102 >= true demand 88 (56 VGPR + 32 AGPR acc)
// -> no spill (R14's lb(256,6) cap 85 < 88 spilled), residency target 5
// waves/SIMD to cover A-load latency with TLP.
// ---------------------------------------------------------------------------
__global__ __launch_bounds__(256, 5)
void conv4d_mfma(const u16* __restrict__ xh, const u16* __restrict__ wl_,
                 const float* __restrict__ slopes, int sidx, u16* __restrict__ yh)
{
    const int blk = blockIdx.x;
    // XCD swizzle: xcd = blk&7 owns d1 rows {2*xcd, 2*xcd+1}, n-major order.
    const int xcd = blk & 7;
    const int s = blk >> 3;
    const int n = s >> 5;
    const int t_ = s & 31;
    const int d1 = xcd * 2 + (t_ >> 4);
    const int d2 = t_ & 15;

    const int lane = threadIdx.x & 63, wv = threadIdx.x >> 6;
    const int l15 = lane & 15, q = lane >> 4;

    f32x4 acc[4][2];
#pragma unroll
    for (int f = 0; f < 4; ++f)
#pragma unroll
        for (int nf = 0; nf < 2; ++nf)
            acc[f][nf] = (f32x4){0.f, 0.f, 0.f, 0.f};

    const size_t nbase = (size_t)n * 256 * 8192;
    const int aoff = l15 * 32 + q * 8;       // within-plane frag offset (dd=1)
    const half8 zero8 = (half8)(_Float16)0;

#pragma unroll 1
    for (int da = 0; da < 3; ++da) {
        const int a = d1 + da - 1;
        if ((unsigned)a > 15u) continue;     // block-uniform: pad plane = 0
#pragma unroll 1
        for (int db = 0; db < 3; ++db) {
            const int b = d2 + db - 1;
            if ((unsigned)b > 15u) continue;
            const u16* Hp = xh + nbase + (size_t)(a * 16 + b) * 8192;
            const u16* wt0 = wl_ + (size_t)((da * 3 + db) * 9) * 1024;

            // base A-frags (dd=1, col=l15): rows wv*4-1 .. wv*4+4
            half8 ax[6];
#pragma unroll
            for (int r6 = 0; r6 < 6; ++r6) {
                const int d3c = (wv * 4 + r6 - 1) & 15;   // wrap; edges zeroed
                ax[r6] = *(const half8*)(Hp + d3c * 512 + aoff);
            }
            if (wv == 0)      ax[0] = zero8;  // d3 = -1 pad row
            else if (wv == 3) ax[5] = zero8;  // d3 = 16 pad row

            // ---- dd outer: shift A once, 3 dc taps reuse it ----
#pragma unroll
            for (int dd = 0; dd < 3; ++dd) {
                half8 As[6];
#pragma unroll
                for (int r6 = 0; r6 < 6; ++r6) {
                    if (dd == 0)      As[r6] = dpp8<0x111>(ax[r6]); // col-1
                    else if (dd == 1) As[r6] = ax[r6];
                    else              As[r6] = dpp8<0x101>(ax[r6]); // col+1
                }
#pragma unroll
                for (int dc = 0; dc < 3; ++dc) {
                    const u16* wb = wt0 + (dc * 3 + dd) * 1024;
                    half8 B0 = *(const half8*)(wb + aoff);
                    half8 B1 = *(const half8*)(wb + 512 + aoff);
#pragma unroll
                    for (int f = 0; f < 4; ++f) {
                        acc[f][0] = __builtin_amdgcn_mfma_f32_16x16x32_f16(As[f + dc], B0, acc[f][0], 0, 0, 0);
                        acc[f][1] = __builtin_amdgcn_mfma_f32_16x16x32_f16(As[f + dc], B1, acc[f][1], 0, 0, 0);
                    }
                }
            }
        }
    }

    // ---- epilogue: PReLU, fp16 pack, store to [pos][ch] buffer ----
    const float slope = slopes[sidx];
    u16* Hb = yh + ((size_t)(n * 256) + d1 * 16 + d2) * 8192;
#pragma unroll
    for (int f = 0; f < 4; ++f) {
#pragma unroll
        for (int nf = 0; nf < 2; ++nf) {
            const int o = nf * 16 + l15;
#pragma unroll
            for (int j = 0; j < 4; ++j) {
                float v = acc[f][nf][j];
                v = v >= 0.f ? v : slope * v;
                const int pos = (wv * 4 + f) * 16 + q * 4 + j;
                Hb[pos * 32 + o] = f2h_bits(v);
            }
        }
    }
}

// ---------------------------------------------------------------------------
// Layer 0: IC=2, fp32 math, PReLU; original x layout in, fp16 out.
// ---------------------------------------------------------------------------
__global__ __launch_bounds__(256, 4)
void conv4d_c2(const float* __restrict__ x, const float* __restrict__ wp,
               const float* __restrict__ slopes, u16* __restrict__ yh)
{
    const int blk = blockIdx.x;
    const int d2 = blk & 15, d1 = (blk >> 4) & 15, n = blk >> 8;
    const int tid = threadIdx.x;
    const int c = tid >> 4, d = tid & 15;

    __shared__ float xs[3][3][18][18];
    float* xsf = &xs[0][0][0][0];
    for (int idx = tid; idx < 3 * 3 * 18 * 18; idx += 256) xsf[idx] = 0.0f;

    float acc[32];
#pragma unroll
    for (int o = 0; o < 32; ++o) acc[o] = 0.0f;

    for (int i = 0; i < 2; ++i) {
#pragma unroll
        for (int da = 0; da < 3; ++da) {
            const int a = d1 + da - 1;
#pragma unroll
            for (int db = 0; db < 3; ++db) {
                const int b = d2 + db - 1;
                float v = 0.0f;
                if (a >= 0 && a < L && b >= 0 && b < L)
                    v = x[(((size_t)(n * 2 + i) * L + a) * L + b) * PLANE + c * L + d];
                xs[da][db][c + 1][d + 1] = v;
            }
        }
        __syncthreads();

        const float* wpi = wp + (size_t)i * 81 * 32;
#pragma unroll 1
        for (int da = 0; da < 3; ++da) {
#pragma unroll 1
            for (int db = 0; db < 3; ++db) {
                float xv[3][3];
#pragma unroll
                for (int dc = 0; dc < 3; ++dc)
#pragma unroll
                    for (int dd = 0; dd < 3; ++dd)
                        xv[dc][dd] = xs[da][db][c + dc][d + dd];

                const float* wt = wpi + (da * 3 + db) * 9 * 32;
#pragma unroll
                for (int dc = 0; dc < 3; ++dc) {
#pragma unroll
                    for (int dd = 0; dd < 3; ++dd) {
                        const float* wr = wt + (dc * 3 + dd) * 32;
#pragma unroll
                        for (int o = 0; o < 32; ++o)
                            acc[o] = fmaf(xv[dc][dd], wr[o], acc[o]);
                    }
                }
            }
        }
        __syncthreads();
    }

    const float slope = slopes[0];
    u16* Hb = yh + ((size_t)(n * 256) + d1 * 16 + d2) * 8192 + (size_t)tid * 32;
    short8 hs[4];
#pragma unroll
    for (int k = 0; k < 4; ++k)
#pragma unroll
        for (int j = 0; j < 8; ++j) {
            float v = acc[k * 8 + j];
            v = v >= 0.f ? v : slope * v;
            hs[k][j] = (short)f2h_bits(v);
        }
#pragma unroll
    for (int k = 0; k < 4; ++k)
        *(short8*)(Hb + k * 8) = hs[k];
}

// ---------------------------------------------------------------------------
// Final layer: IC=32, OC=2 (padded to 16), no PReLU. MFMA, NO LDS/barriers.
// lb(256,4): cap 128 >> demand ~68 unified — R12-proven.
// ---------------------------------------------------------------------------
__global__ __launch_bounds__(256, 4)
void conv4d_out(const u16* __restrict__ xh, const u16* __restrict__ w5,
                float* __restrict__ out)
{
    const int blk = blockIdx.x;
    const int xcd = blk & 7;      // same swizzle as hidden layers (L2 locality)
    const int s = blk >> 3;
    const int n = s >> 5;
    const int t_ = s & 31;
    const int d1 = xcd * 2 + (t_ >> 4);
    const int d2 = t_ & 15;

    const int lane = threadIdx.x & 63, wv = threadIdx.x >> 6;
    const int l15 = lane & 15, q = lane >> 4;

    f32x4 acc[4];
#pragma unroll
    for (int f = 0; f < 4; ++f) acc[f] = (f32x4){0.f, 0.f, 0.f, 0.f};

    const size_t nbase = (size_t)n * 256 * 8192;
    const int aoff = l15 * 32 + q * 8;
    const half8 zero8 = (half8)(_Float16)0;
    const int boff = l15 * 32 + q * 8;    // B[n=l15][k=q*8..], 512 u16/tap

#pragma unroll 1
    for (int da = 0; da < 3; ++da) {
        const int a = d1 + da - 1;
        if ((unsigned)a > 15u) continue;
#pragma unroll 1
        for (int db = 0; db < 3; ++db) {
            const int b = d2 + db - 1;
            if ((unsigned)b > 15u) continue;
            const u16* Hp = xh + nbase + (size_t)(a * 16 + b) * 8192;
            const u16* wt0 = w5 + (size_t)((da * 3 + db) * 9) * 512;

            half8 ax[6];
#pragma unroll
            for (int r6 = 0; r6 < 6; ++r6) {
                const int d3c = (wv * 4 + r6 - 1) & 15;
                ax[r6] = *(const half8*)(Hp + d3c * 512 + aoff);
            }
            if (wv == 0)      ax[0] = zero8;
            else if (wv == 3) ax[5] = zero8;

#pragma unroll
            for (int dd = 0; dd < 3; ++dd) {
                half8 As[6];
#pragma unroll
                for (int r6 = 0; r6 < 6; ++r6) {
                    if (dd == 0)      As[r6] = dpp8<0x111>(ax[r6]);
                    else if (dd == 1) As[r6] = ax[r6];
                    else              As[r6] = dpp8<0x101>(ax[r6]);
                }
#pragma unroll
                for (int dc = 0; dc < 3; ++dc) {
                    const u16* wb = wt0 + (dc * 3 + dd) * 512;
                    half8 B0 = *(const half8*)(wb + boff);
#pragma unroll
                    for (int f = 0; f < 4; ++f)
                        acc[f] = __builtin_amdgcn_mfma_f32_16x16x32_f16(As[f + dc], B0, acc[f], 0, 0, 0);
                }
            }
        }
    }

    // ---- epilogue: lanes l15<2 hold valid oc; D row = d4 = q*4+j ----
    if (l15 < 2) {
        float* ob = out + (size_t)(n * 2 + l15) * VOL + (size_t)(d1 * 16 + d2) * 256;
#pragma unroll
        for (int f = 0; f < 4; ++f) {
            const int d3 = wv * 4 + f;
            *(f32x4*)(ob + d3 * 16 + q * 4) = acc[f];
        }
    }
}

extern "C" void kernel_launch(void* const* d_in, const int* in_sizes, int n_in,
                              void* d_out, int out_size, void* d_ws, size_t ws_size,
                              hipStream_t stream)
{
    (void)in_sizes; (void)n_in; (void)out_size; (void)ws_size;
    const float* x      = (const float*)d_in[0];
    const float* k0     = (const float*)d_in[1];
    const float* k1     = (const float*)d_in[2];
    const float* k2     = (const float*)d_in[3];
    const float* k3     = (const float*)d_in[4];
    const float* k4     = (const float*)d_in[5];
    const float* k5     = (const float*)d_in[6];
    const float* slopes = (const float*)d_in[7];
    float* outp = (float*)d_out;

    // fp16 activation ping-pong buffers in d_ws: 33.5 MB each; wp5 after.
    u16* b0 = (u16*)d_ws;
    u16* b1 = b0 + (size_t)2048 * 8192;
    u16* wp5 = b1 + (size_t)2048 * 8192;    // 81*512 u16 = 83 KB

    // Hidden/layer0 weights in d_out (consumed before conv4d_out writes it):
    u16* wpk = (u16*)d_out;                 // 4*81*1024 u16 = 663 KB
    float* wp0 = outp + 165888;             // 5184 fp32 after that

    pack_h1<<<dim3(1296), 256, 0, stream>>>(k1, k2, k3, k4, wpk);
    pack_w0<<<dim3(21), 256, 0, stream>>>(k0, wp0);
    pack_k5<<<dim3(162), 256, 0, stream>>>(k5, wp5);

    const dim3 grid(8 * L * L);
    const dim3 block(256);

    conv4d_c2<<<grid, block, 0, stream>>>(x, wp0, slopes, b0);
    conv4d_mfma<<<grid, block, 0, stream>>>(b0, wpk + (size_t)0 * 81 * 1024, slopes, 1, b1);
    conv4d_mfma<<<grid, block, 0, stream>>>(b1, wpk + (size_t)1 * 81 * 1024, slopes, 2, b0);
    conv4d_mfma<<<grid, block, 0, stream>>>(b0, wpk + (size_t)2 * 81 * 1024, slopes, 3, b1);
    conv4d_mfma<<<grid, block, 0, stream>>>(b1, wpk + (size_t)3 * 81 * 1024, slopes, 4, b0);
    conv4d_out<<<grid, block, 0, stream>>>(b0, wp5, outp);
}

// Round 16
// 612.027 us; speedup vs baseline: 1.7868x; 1.2170x over previous
//
#include <hip/hip_runtime.h>
#include <cstddef>

#define L 16
#define PLANE 256
#define VOL 65536

typedef __attribute__((ext_vector_type(8))) short short8;
typedef __attribute__((ext_vector_type(8))) _Float16 half8;
typedef __attribute__((ext_vector_type(4))) float f32x4;
typedef __attribute__((ext_vector_type(4))) int i32x4;
typedef unsigned int u32;
typedef unsigned short u16;

__device__ __forceinline__ u16 f2h_bits(float f) {
    _Float16 h = (_Float16)f;             // RTN
    return __builtin_bit_cast(u16, h);
}

// DPP lane-shift within 16-lane rows; bound_ctrl + old=0 -> zero fill at row
// edges == SAME-padding for the d4 dimension, for free.
template <int CTRL>
__device__ __forceinline__ int dppmov(int v) {
    return __builtin_amdgcn_update_dpp(0, v, CTRL, 0xf, 0xf, true);
}
template <int CTRL>
__device__ __forceinline__ half8 dpp8(half8 v) {
    i32x4 u = __builtin_bit_cast(i32x4, v), r;
    r[0] = dppmov<CTRL>(u[0]); r[1] = dppmov<CTRL>(u[1]);
    r[2] = dppmov<CTRL>(u[2]); r[3] = dppmov<CTRL>(u[3]);
    return __builtin_bit_cast(half8, r);
}

// ---------------------------------------------------------------------------
// Pack layer0 (IC=2) weights to fp32 [i][tap][o].
// ---------------------------------------------------------------------------
__global__ void pack_w0(const float* __restrict__ k0, float* __restrict__ dst)
{
    int idx = blockIdx.x * 256 + threadIdx.x;   // (i*81 + t)*32 + o
    if (idx >= 2 * 81 * 32) return;
    int o = idx & 31;
    int t = (idx >> 5) % 81;
    int i = idx / (32 * 81);
    dst[idx] = k0[(size_t)(o * 2 + i) * 81 + t];
}

// ---------------------------------------------------------------------------
// Pack k1..k4 to SINGLE fp16: wpk[layer][tap][o][i], 81*1024 u16 per layer.
// (R11: fp16 RTN on hidden weights moved absmax by exactly zero.)
// ---------------------------------------------------------------------------
__global__ void pack_h1(const float* __restrict__ k1, const float* __restrict__ k2,
                        const float* __restrict__ k3, const float* __restrict__ k4,
                        u16* __restrict__ dst)
{
    int idx = blockIdx.x * 256 + threadIdx.x;
    if (idx >= 4 * 81 * 1024) return;
    int layer = idx / (81 * 1024);
    int r = idx % (81 * 1024);
    int t = r / 1024;
    int oi = r % 1024;                  // o*32 + i
    int o = oi >> 5, i = oi & 31;
    const float* src = layer == 0 ? k1 : layer == 1 ? k2 : layer == 2 ? k3 : k4;
    float w = src[(size_t)(o * 32 + i) * 81 + t];
    dst[((size_t)layer * 81 + t) * 1024 + oi] = f2h_bits(w);
}

// ---------------------------------------------------------------------------
// Pack k5 (OC=2) to fp16 padded to 16: wp5[tap][n=16][k=32], 81*512 u16.
// ---------------------------------------------------------------------------
__global__ void pack_k5(const float* __restrict__ k5, u16* __restrict__ dst)
{
    int idx = blockIdx.x * 256 + threadIdx.x;   // t*512 + o*32 + i
    if (idx >= 81 * 512) return;
    int t = idx >> 9;
    int oi = idx & 511;
    int o = oi >> 5, i = oi & 31;
    float w = (o < 2) ? k5[(size_t)(o * 32 + i) * 81 + t] : 0.0f;
    dst[idx] = f2h_bits(w);
}

// ---------------------------------------------------------------------------
// MFMA conv layer, IC=OC=32, PReLU. fp16 SINGLE-pass, NO LDS, NO barriers.
// Activations [n][d1][d2][pos=d3*16+d4][ch]. Per plane: 6 A b128 loads,
// dd-outer with once-per-dd DPP-shifted A array, 9 taps x 8 MFMA.
// lb(256,3): R12-proven optimum. True unified demand ~88+ (56 VGPR + 32
// AGPR acc); EVERY tighter bound (R13 2-tile, R14 lb6, R15 lb5) spilled and
// regressed; occupancy is footprint-limited at ~37%, not lb-limited (R15).
// ---------------------------------------------------------------------------
__global__ __launch_bounds__(256, 3)
void conv4d_mfma(const u16* __restrict__ xh, const u16* __restrict__ wl_,
                 const float* __restrict__ slopes, int sidx, u16* __restrict__ yh)
{
    const int blk = blockIdx.x;
    // XCD swizzle: xcd = blk&7 owns d1 rows {2*xcd, 2*xcd+1}, n-major order.
    const int xcd = blk & 7;
    const int s = blk >> 3;
    const int n = s >> 5;
    const int t_ = s & 31;
    const int d1 = xcd * 2 + (t_ >> 4);
    const int d2 = t_ & 15;

    const int lane = threadIdx.x & 63, wv = threadIdx.x >> 6;
    const int l15 = lane & 15, q = lane >> 4;

    f32x4 acc[4][2];
#pragma unroll
    for (int f = 0; f < 4; ++f)
#pragma unroll
        for (int nf = 0; nf < 2; ++nf)
            acc[f][nf] = (f32x4){0.f, 0.f, 0.f, 0.f};

    const size_t nbase = (size_t)n * 256 * 8192;
    const int aoff = l15 * 32 + q * 8;       // within-plane frag offset (dd=1)
    const half8 zero8 = (half8)(_Float16)0;

#pragma unroll 1
    for (int da = 0; da < 3; ++da) {
        const int a = d1 + da - 1;
        if ((unsigned)a > 15u) continue;     // block-uniform: pad plane = 0
#pragma unroll 1
        for (int db = 0; db < 3; ++db) {
            const int b = d2 + db - 1;
            if ((unsigned)b > 15u) continue;
            const u16* Hp = xh + nbase + (size_t)(a * 16 + b) * 8192;
            const u16* wt0 = wl_ + (size_t)((da * 3 + db) * 9) * 1024;

            // base A-frags (dd=1, col=l15): rows wv*4-1 .. wv*4+4
            half8 ax[6];
#pragma unroll
            for (int r6 = 0; r6 < 6; ++r6) {
                const int d3c = (wv * 4 + r6 - 1) & 15;   // wrap; edges zeroed
                ax[r6] = *(const half8*)(Hp + d3c * 512 + aoff);
            }
            if (wv == 0)      ax[0] = zero8;  // d3 = -1 pad row
            else if (wv == 3) ax[5] = zero8;  // d3 = 16 pad row

            // ---- dd outer: shift A once, 3 dc taps reuse it ----
#pragma unroll
            for (int dd = 0; dd < 3; ++dd) {
                half8 As[6];
#pragma unroll
                for (int r6 = 0; r6 < 6; ++r6) {
                    if (dd == 0)      As[r6] = dpp8<0x111>(ax[r6]); // col-1
                    else if (dd == 1) As[r6] = ax[r6];
                    else              As[r6] = dpp8<0x101>(ax[r6]); // col+1
                }
#pragma unroll
                for (int dc = 0; dc < 3; ++dc) {
                    const u16* wb = wt0 + (dc * 3 + dd) * 1024;
                    half8 B0 = *(const half8*)(wb + aoff);
                    half8 B1 = *(const half8*)(wb + 512 + aoff);
#pragma unroll
                    for (int f = 0; f < 4; ++f) {
                        acc[f][0] = __builtin_amdgcn_mfma_f32_16x16x32_f16(As[f + dc], B0, acc[f][0], 0, 0, 0);
                        acc[f][1] = __builtin_amdgcn_mfma_f32_16x16x32_f16(As[f + dc], B1, acc[f][1], 0, 0, 0);
                    }
                }
            }
        }
    }

    // ---- epilogue: PReLU, fp16 pack, store to [pos][ch] buffer ----
    const float slope = slopes[sidx];
    u16* Hb = yh + ((size_t)(n * 256) + d1 * 16 + d2) * 8192;
#pragma unroll
    for (int f = 0; f < 4; ++f) {
#pragma unroll
        for (int nf = 0; nf < 2; ++nf) {
            const int o = nf * 16 + l15;
#pragma unroll
            for (int j = 0; j < 4; ++j) {
                float v = acc[f][nf][j];
                v = v >= 0.f ? v : slope * v;
                const int pos = (wv * 4 + f) * 16 + q * 4 + j;
                Hb[pos * 32 + o] = f2h_bits(v);
            }
        }
    }
}

// ---------------------------------------------------------------------------
// Layer 0: IC=2, fp32 math, PReLU; original x layout in, fp16 out.
// ---------------------------------------------------------------------------
__global__ __launch_bounds__(256, 4)
void conv4d_c2(const float* __restrict__ x, const float* __restrict__ wp,
               const float* __restrict__ slopes, u16* __restrict__ yh)
{
    const int blk = blockIdx.x;
    const int d2 = blk & 15, d1 = (blk >> 4) & 15, n = blk >> 8;
    const int tid = threadIdx.x;
    const int c = tid >> 4, d = tid & 15;

    __shared__ float xs[3][3][18][18];
    float* xsf = &xs[0][0][0][0];
    for (int idx = tid; idx < 3 * 3 * 18 * 18; idx += 256) xsf[idx] = 0.0f;

    float acc[32];
#pragma unroll
    for (int o = 0; o < 32; ++o) acc[o] = 0.0f;

    for (int i = 0; i < 2; ++i) {
#pragma unroll
        for (int da = 0; da < 3; ++da) {
            const int a = d1 + da - 1;
#pragma unroll
            for (int db = 0; db < 3; ++db) {
                const int b = d2 + db - 1;
                float v = 0.0f;
                if (a >= 0 && a < L && b >= 0 && b < L)
                    v = x[(((size_t)(n * 2 + i) * L + a) * L + b) * PLANE + c * L + d];
                xs[da][db][c + 1][d + 1] = v;
            }
        }
        __syncthreads();

        const float* wpi = wp + (size_t)i * 81 * 32;
#pragma unroll 1
        for (int da = 0; da < 3; ++da) {
#pragma unroll 1
            for (int db = 0; db < 3; ++db) {
                float xv[3][3];
#pragma unroll
                for (int dc = 0; dc < 3; ++dc)
#pragma unroll
                    for (int dd = 0; dd < 3; ++dd)
                        xv[dc][dd] = xs[da][db][c + dc][d + dd];

                const float* wt = wpi + (da * 3 + db) * 9 * 32;
#pragma unroll
                for (int dc = 0; dc < 3; ++dc) {
#pragma unroll
                    for (int dd = 0; dd < 3; ++dd) {
                        const float* wr = wt + (dc * 3 + dd) * 32;
#pragma unroll
                        for (int o = 0; o < 32; ++o)
                            acc[o] = fmaf(xv[dc][dd], wr[o], acc[o]);
                    }
                }
            }
        }
        __syncthreads();
    }

    const float slope = slopes[0];
    u16* Hb = yh + ((size_t)(n * 256) + d1 * 16 + d2) * 8192 + (size_t)tid * 32;
    short8 hs[4];
#pragma unroll
    for (int k = 0; k < 4; ++k)
#pragma unroll
        for (int j = 0; j < 8; ++j) {
            float v = acc[k * 8 + j];
            v = v >= 0.f ? v : slope * v;
            hs[k][j] = (short)f2h_bits(v);
        }
#pragma unroll
    for (int k = 0; k < 4; ++k)
        *(short8*)(Hb + k * 8) = hs[k];
}

// ---------------------------------------------------------------------------
// Final layer: IC=32, OC=2 (padded to 16), no PReLU. MFMA, NO LDS/barriers.
// lb(256,4): cap 128 >> demand ~68 unified — R12-proven.
// ---------------------------------------------------------------------------
__global__ __launch_bounds__(256, 4)
void conv4d_out(const u16* __restrict__ xh, const u16* __restrict__ w5,
                float* __restrict__ out)
{
    const int blk = blockIdx.x;
    const int xcd = blk & 7;      // same swizzle as hidden layers (L2 locality)
    const int s = blk >> 3;
    const int n = s >> 5;
    const int t_ = s & 31;
    const int d1 = xcd * 2 + (t_ >> 4);
    const int d2 = t_ & 15;

    const int lane = threadIdx.x & 63, wv = threadIdx.x >> 6;
    const int l15 = lane & 15, q = lane >> 4;

    f32x4 acc[4];
#pragma unroll
    for (int f = 0; f < 4; ++f) acc[f] = (f32x4){0.f, 0.f, 0.f, 0.f};

    const size_t nbase = (size_t)n * 256 * 8192;
    const int aoff = l15 * 32 + q * 8;
    const half8 zero8 = (half8)(_Float16)0;
    const int boff = l15 * 32 + q * 8;    // B[n=l15][k=q*8..], 512 u16/tap

#pragma unroll 1
    for (int da = 0; da < 3; ++da) {
        const int a = d1 + da - 1;
        if ((unsigned)a > 15u) continue;
#pragma unroll 1
        for (int db = 0; db < 3; ++db) {
            const int b = d2 + db - 1;
            if ((unsigned)b > 15u) continue;
            const u16* Hp = xh + nbase + (size_t)(a * 16 + b) * 8192;
            const u16* wt0 = w5 + (size_t)((da * 3 + db) * 9) * 512;

            half8 ax[6];
#pragma unroll
            for (int r6 = 0; r6 < 6; ++r6) {
                const int d3c = (wv * 4 + r6 - 1) & 15;
                ax[r6] = *(const half8*)(Hp + d3c * 512 + aoff);
            }
            if (wv == 0)      ax[0] = zero8;
            else if (wv == 3) ax[5] = zero8;

#pragma unroll
            for (int dd = 0; dd < 3; ++dd) {
                half8 As[6];
#pragma unroll
                for (int r6 = 0; r6 < 6; ++r6) {
                    if (dd == 0)      As[r6] = dpp8<0x111>(ax[r6]);
                    else if (dd == 1) As[r6] = ax[r6];
                    else              As[r6] = dpp8<0x101>(ax[r6]);
                }
#pragma unroll
                for (int dc = 0; dc < 3; ++dc) {
                    const u16* wb = wt0 + (dc * 3 + dd) * 512;
                    half8 B0 = *(const half8*)(wb + boff);
#pragma unroll
                    for (int f = 0; f < 4; ++f)
                        acc[f] = __builtin_amdgcn_mfma_f32_16x16x32_f16(As[f + dc], B0, acc[f], 0, 0, 0);
                }
            }
        }
    }

    // ---- epilogue: lanes l15<2 hold valid oc; D row = d4 = q*4+j ----
    if (l15 < 2) {
        float* ob = out + (size_t)(n * 2 + l15) * VOL + (size_t)(d1 * 16 + d2) * 256;
#pragma unroll
        for (int f = 0; f < 4; ++f) {
            const int d3 = wv * 4 + f;
            *(f32x4*)(ob + d3 * 16 + q * 4) = acc[f];
        }
    }
}

extern "C" void kernel_launch(void* const* d_in, const int* in_sizes, int n_in,
                              void* d_out, int out_size, void* d_ws, size_t ws_size,
                              hipStream_t stream)
{
    (void)in_sizes; (void)n_in; (void)out_size; (void)ws_size;
    const float* x      = (const float*)d_in[0];
    const float* k0     = (const float*)d_in[1];
    const float* k1     = (const float*)d_in[2];
    const float* k2     = (const float*)d_in[3];
    const float* k3     = (const float*)d_in[4];
    const float* k4     = (const float*)d_in[5];
    const float* k5     = (const float*)d_in[6];
    const float* slopes = (const float*)d_in[7];
    float* outp = (float*)d_out;

    // fp16 activation ping-pong buffers in d_ws: 33.5 MB each; wp5 after.
    u16* b0 = (u16*)d_ws;
    u16* b1 = b0 + (size_t)2048 * 8192;
    u16* wp5 = b1 + (size_t)2048 * 8192;    // 81*512 u16 = 83 KB

    // Hidden/layer0 weights in d_out (consumed before conv4d_out writes it):
    u16* wpk = (u16*)d_out;                 // 4*81*1024 u16 = 663 KB
    float* wp0 = outp + 165888;             // 5184 fp32 after that

    pack_h1<<<dim3(1296), 256, 0, stream>>>(k1, k2, k3, k4, wpk);
    pack_w0<<<dim3(21), 256, 0, stream>>>(k0, wp0);
    pack_k5<<<dim3(162), 256, 0, stream>>>(k5, wp5);

    const dim3 grid(8 * L * L);
    const dim3 block(256);

    conv4d_c2<<<grid, block, 0, stream>>>(x, wp0, slopes, b0);
    conv4d_mfma<<<grid, block, 0, stream>>>(b0, wpk + (size_t)0 * 81 * 1024, slopes, 1, b1);
    conv4d_mfma<<<grid, block, 0, stream>>>(b1, wpk + (size_t)1 * 81 * 1024, slopes, 2, b0);
    conv4d_mfma<<<grid, block, 0, stream>>>(b0, wpk + (size_t)2 * 81 * 1024, slopes, 3, b1);
    conv4d_mfma<<<grid, block, 0, stream>>>(b1, wpk + (size_t)3 * 81 * 1024, slopes, 4, b0);
    conv4d_out<<<grid, block, 0, stream>>>(b0, wp5, outp);
}

// Round 17
// 488.385 us; speedup vs baseline: 2.2391x; 1.2532x over previous
//
#include <hip/hip_runtime.h>
#include <cstddef>

#define L 16
#define PLANE 256
#define VOL 65536

typedef __attribute__((ext_vector_type(8))) short short8;
typedef __attribute__((ext_vector_type(8))) _Float16 half8;
typedef __attribute__((ext_vector_type(4))) float f32x4;
typedef __attribute__((ext_vector_type(4))) int i32x4;
typedef unsigned int u32;
typedef unsigned short u16;

__device__ __forceinline__ u16 f2h_bits(float f) {
    _Float16 h = (_Float16)f;             // RTN
    return __builtin_bit_cast(u16, h);
}

// DPP lane-shift within 16-lane rows; bound_ctrl + old=0 -> zero fill at row
// edges == SAME-padding for the d4 dimension, for free.
template <int CTRL>
__device__ __forceinline__ int dppmov(int v) {
    return __builtin_amdgcn_update_dpp(0, v, CTRL, 0xf, 0xf, true);
}
template <int CTRL>
__device__ __forceinline__ half8 dpp8(half8 v) {
    i32x4 u = __builtin_bit_cast(i32x4, v), r;
    r[0] = dppmov<CTRL>(u[0]); r[1] = dppmov<CTRL>(u[1]);
    r[2] = dppmov<CTRL>(u[2]); r[3] = dppmov<CTRL>(u[3]);
    return __builtin_bit_cast(half8, r);
}

// Async global->LDS, 16B per lane: LDS dest = uniform base + lane*16.
__device__ __forceinline__ void gload_lds16(const u16* g, u16* l) {
    __builtin_amdgcn_global_load_lds(
        (const __attribute__((address_space(1))) void*)g,
        (__attribute__((address_space(3))) void*)l, 16, 0, 0);
}

// ---------------------------------------------------------------------------
// Pack layer0 (IC=2) weights to fp32 [i][tap][o].
// ---------------------------------------------------------------------------
__global__ void pack_w0(const float* __restrict__ k0, float* __restrict__ dst)
{
    int idx = blockIdx.x * 256 + threadIdx.x;   // (i*81 + t)*32 + o
    if (idx >= 2 * 81 * 32) return;
    int o = idx & 31;
    int t = (idx >> 5) % 81;
    int i = idx / (32 * 81);
    dst[idx] = k0[(size_t)(o * 2 + i) * 81 + t];
}

// ---------------------------------------------------------------------------
// Pack k1..k4 to SINGLE fp16: wpk[layer][tap][o][i], 81*1024 u16 per layer.
// (R11: fp16 RTN on hidden weights moved absmax by exactly zero.)
// ---------------------------------------------------------------------------
__global__ void pack_h1(const float* __restrict__ k1, const float* __restrict__ k2,
                        const float* __restrict__ k3, const float* __restrict__ k4,
                        u16* __restrict__ dst)
{
    int idx = blockIdx.x * 256 + threadIdx.x;
    if (idx >= 4 * 81 * 1024) return;
    int layer = idx / (81 * 1024);
    int r = idx % (81 * 1024);
    int t = r / 1024;
    int oi = r % 1024;                  // o*32 + i
    int o = oi >> 5, i = oi & 31;
    const float* src = layer == 0 ? k1 : layer == 1 ? k2 : layer == 2 ? k3 : k4;
    float w = src[(size_t)(o * 32 + i) * 81 + t];
    dst[((size_t)layer * 81 + t) * 1024 + oi] = f2h_bits(w);
}

// ---------------------------------------------------------------------------
// Pack k5 (OC=2) to fp16 padded to 16: wp5[tap][n=16][k=32], 81*512 u16.
// ---------------------------------------------------------------------------
__global__ void pack_k5(const float* __restrict__ k5, u16* __restrict__ dst)
{
    int idx = blockIdx.x * 256 + threadIdx.x;   // t*512 + o*32 + i
    if (idx >= 81 * 512) return;
    int t = idx >> 9;
    int oi = idx & 511;
    int o = oi >> 5, i = oi & 31;
    float w = (o < 2) ? k5[(size_t)(o * 32 + i) * 81 + t] : 0.0f;
    dst[idx] = f2h_bits(w);
}

// ---------------------------------------------------------------------------
// MFMA conv layer, IC=OC=32, PReLU. fp16 single-pass. A path: no-LDS,
// direct global b128 + DPP shifts (R12-proven). B path: per-plane 18 KB
// (9 contiguous taps) staged into a 2x18KB LDS double-buffer via async
// global_load_lds (width 16); one barrier per plane publishes the buffer
// while the next plane's staging flies during compute. Rationale: the
// layer's 166 KB B-stream thrashes the 32 KB L1, so in-loop B loads were
// ~L2-latency on the dependent path.
// ---------------------------------------------------------------------------
__global__ __launch_bounds__(256, 3)
void conv4d_mfma(const u16* __restrict__ xh, const u16* __restrict__ wl_,
                 const float* __restrict__ slopes, int sidx, u16* __restrict__ yh)
{
    const int blk = blockIdx.x;
    // XCD swizzle: xcd = blk&7 owns d1 rows {2*xcd, 2*xcd+1}, n-major order.
    const int xcd = blk & 7;
    const int s = blk >> 3;
    const int n = s >> 5;
    const int t_ = s & 31;
    const int d1 = xcd * 2 + (t_ >> 4);
    const int d2 = t_ & 15;

    const int lane = threadIdx.x & 63, wv = threadIdx.x >> 6;
    const int l15 = lane & 15, q = lane >> 4;

    __shared__ __attribute__((aligned(16))) u16 bs[2][9216];   // 2 x 18 KB

    f32x4 acc[4][2];
#pragma unroll
    for (int f = 0; f < 4; ++f)
#pragma unroll
        for (int nf = 0; nf < 2; ++nf)
            acc[f][nf] = (f32x4){0.f, 0.f, 0.f, 0.f};

    const size_t nbase = (size_t)n * 256 * 8192;
    const int aoff = l15 * 32 + q * 8;       // within-plane frag offset (dd=1)
    const half8 zero8 = (half8)(_Float16)0;

    // Stage plane p's 9 taps (18 KB, contiguous at wl_ + p*9216) into
    // bs[p&1]. 18 chunks of 1 KB; wave wv takes chunks c ≡ wv (mod 4).
    auto stageB = [&](int p) {
        const u16* src = wl_ + (size_t)p * 9216;
        u16* dst = &bs[p & 1][0];
        for (int c = wv; c < 18; c += 4)
            gload_lds16(src + c * 512 + lane * 8, dst + c * 512);
    };

    stageB(0);

#pragma unroll 1
    for (int p = 0; p < 9; ++p) {
        __syncthreads();                 // publishes bs[p&1] (drains stage p)
        if (p < 8) stageB(p + 1);        // async, lands during compute below

        const int da = p / 3, db = p % 3;
        const int a = d1 + da - 1;
        const int b = d2 + db - 1;
        if ((unsigned)a > 15u || (unsigned)b > 15u) continue;  // pad plane = 0

        const u16* Hp = xh + nbase + (size_t)(a * 16 + b) * 8192;
        const u16* wt0 = &bs[p & 1][0];

        // base A-frags (dd=1, col=l15): rows wv*4-1 .. wv*4+4
        half8 ax[6];
#pragma unroll
        for (int r6 = 0; r6 < 6; ++r6) {
            const int d3c = (wv * 4 + r6 - 1) & 15;   // wrap; edges zeroed
            ax[r6] = *(const half8*)(Hp + d3c * 512 + aoff);
        }
        if (wv == 0)      ax[0] = zero8;  // d3 = -1 pad row
        else if (wv == 3) ax[5] = zero8;  // d3 = 16 pad row

        // ---- dd outer: shift A once, 3 dc taps reuse it; B from LDS ----
#pragma unroll
        for (int dd = 0; dd < 3; ++dd) {
            half8 As[6];
#pragma unroll
            for (int r6 = 0; r6 < 6; ++r6) {
                if (dd == 0)      As[r6] = dpp8<0x111>(ax[r6]); // col-1
                else if (dd == 1) As[r6] = ax[r6];
                else              As[r6] = dpp8<0x101>(ax[r6]); // col+1
            }
#pragma unroll
            for (int dc = 0; dc < 3; ++dc) {
                const u16* wb = wt0 + (dc * 3 + dd) * 1024;
                half8 B0 = *(const half8*)(wb + aoff);
                half8 B1 = *(const half8*)(wb + 512 + aoff);
#pragma unroll
                for (int f = 0; f < 4; ++f) {
                    acc[f][0] = __builtin_amdgcn_mfma_f32_16x16x32_f16(As[f + dc], B0, acc[f][0], 0, 0, 0);
                    acc[f][1] = __builtin_amdgcn_mfma_f32_16x16x32_f16(As[f + dc], B1, acc[f][1], 0, 0, 0);
                }
            }
        }
    }

    // ---- epilogue: PReLU, fp16 pack, store to [pos][ch] buffer ----
    const float slope = slopes[sidx];
    u16* Hb = yh + ((size_t)(n * 256) + d1 * 16 + d2) * 8192;
#pragma unroll
    for (int f = 0; f < 4; ++f) {
#pragma unroll
        for (int nf = 0; nf < 2; ++nf) {
            const int o = nf * 16 + l15;
#pragma unroll
            for (int j = 0; j < 4; ++j) {
                float v = acc[f][nf][j];
                v = v >= 0.f ? v : slope * v;
                const int pos = (wv * 4 + f) * 16 + q * 4 + j;
                Hb[pos * 32 + o] = f2h_bits(v);
            }
        }
    }
}

// ---------------------------------------------------------------------------
// Layer 0: IC=2, fp32 math, PReLU; original x layout in, fp16 out.
// ---------------------------------------------------------------------------
__global__ __launch_bounds__(256, 4)
void conv4d_c2(const float* __restrict__ x, const float* __restrict__ wp,
               const float* __restrict__ slopes, u16* __restrict__ yh)
{
    const int blk = blockIdx.x;
    const int d2 = blk & 15, d1 = (blk >> 4) & 15, n = blk >> 8;
    const int tid = threadIdx.x;
    const int c = tid >> 4, d = tid & 15;

    __shared__ float xs[3][3][18][18];
    float* xsf = &xs[0][0][0][0];
    for (int idx = tid; idx < 3 * 3 * 18 * 18; idx += 256) xsf[idx] = 0.0f;

    float acc[32];
#pragma unroll
    for (int o = 0; o < 32; ++o) acc[o] = 0.0f;

    for (int i = 0; i < 2; ++i) {
#pragma unroll
        for (int da = 0; da < 3; ++da) {
            const int a = d1 + da - 1;
#pragma unroll
            for (int db = 0; db < 3; ++db) {
                const int b = d2 + db - 1;
                float v = 0.0f;
                if (a >= 0 && a < L && b >= 0 && b < L)
                    v = x[(((size_t)(n * 2 + i) * L + a) * L + b) * PLANE + c * L + d];
                xs[da][db][c + 1][d + 1] = v;
            }
        }
        __syncthreads();

        const float* wpi = wp + (size_t)i * 81 * 32;
#pragma unroll 1
        for (int da = 0; da < 3; ++da) {
#pragma unroll 1
            for (int db = 0; db < 3; ++db) {
                float xv[3][3];
#pragma unroll
                for (int dc = 0; dc < 3; ++dc)
#pragma unroll
                    for (int dd = 0; dd < 3; ++dd)
                        xv[dc][dd] = xs[da][db][c + dc][d + dd];

                const float* wt = wpi + (da * 3 + db) * 9 * 32;
#pragma unroll
                for (int dc = 0; dc < 3; ++dc) {
#pragma unroll
                    for (int dd = 0; dd < 3; ++dd) {
                        const float* wr = wt + (dc * 3 + dd) * 32;
#pragma unroll
                        for (int o = 0; o < 32; ++o)
                            acc[o] = fmaf(xv[dc][dd], wr[o], acc[o]);
                    }
                }
            }
        }
        __syncthreads();
    }

    const float slope = slopes[0];
    u16* Hb = yh + ((size_t)(n * 256) + d1 * 16 + d2) * 8192 + (size_t)tid * 32;
    short8 hs[4];
#pragma unroll
    for (int k = 0; k < 4; ++k)
#pragma unroll
        for (int j = 0; j < 8; ++j) {
            float v = acc[k * 8 + j];
            v = v >= 0.f ? v : slope * v;
            hs[k][j] = (short)f2h_bits(v);
        }
#pragma unroll
    for (int k = 0; k < 4; ++k)
        *(short8*)(Hb + k * 8) = hs[k];
}

// ---------------------------------------------------------------------------
// Final layer: IC=32, OC=2 (padded to 16), no PReLU. MFMA, NO LDS/barriers.
// lb(256,4): cap 128 >> demand ~68 unified — R12-proven.
// ---------------------------------------------------------------------------
__global__ __launch_bounds__(256, 4)
void conv4d_out(const u16* __restrict__ xh, const u16* __restrict__ w5,
                float* __restrict__ out)
{
    const int blk = blockIdx.x;
    const int xcd = blk & 7;      // same swizzle as hidden layers (L2 locality)
    const int s = blk >> 3;
    const int n = s >> 5;
    const int t_ = s & 31;
    const int d1 = xcd * 2 + (t_ >> 4);
    const int d2 = t_ & 15;

    const int lane = threadIdx.x & 63, wv = threadIdx.x >> 6;
    const int l15 = lane & 15, q = lane >> 4;

    f32x4 acc[4];
#pragma unroll
    for (int f = 0; f < 4; ++f) acc[f] = (f32x4){0.f, 0.f, 0.f, 0.f};

    const size_t nbase = (size_t)n * 256 * 8192;
    const int aoff = l15 * 32 + q * 8;
    const half8 zero8 = (half8)(_Float16)0;
    const int boff = l15 * 32 + q * 8;    // B[n=l15][k=q*8..], 512 u16/tap

#pragma unroll 1
    for (int da = 0; da < 3; ++da) {
        const int a = d1 + da - 1;
        if ((unsigned)a > 15u) continue;
#pragma unroll 1
        for (int db = 0; db < 3; ++db) {
            const int b = d2 + db - 1;
            if ((unsigned)b > 15u) continue;
            const u16* Hp = xh + nbase + (size_t)(a * 16 + b) * 8192;
            const u16* wt0 = w5 + (size_t)((da * 3 + db) * 9) * 512;

            half8 ax[6];
#pragma unroll
            for (int r6 = 0; r6 < 6; ++r6) {
                const int d3c = (wv * 4 + r6 - 1) & 15;
                ax[r6] = *(const half8*)(Hp + d3c * 512 + aoff);
            }
            if (wv == 0)      ax[0] = zero8;
            else if (wv == 3) ax[5] = zero8;

#pragma unroll
            for (int dd = 0; dd < 3; ++dd) {
                half8 As[6];
#pragma unroll
                for (int r6 = 0; r6 < 6; ++r6) {
                    if (dd == 0)      As[r6] = dpp8<0x111>(ax[r6]);
                    else if (dd == 1) As[r6] = ax[r6];
                    else              As[r6] = dpp8<0x101>(ax[r6]);
                }
#pragma unroll
                for (int dc = 0; dc < 3; ++dc) {
                    const u16* wb = wt0 + (dc * 3 + dd) * 512;
                    half8 B0 = *(const half8*)(wb + boff);
#pragma unroll
                    for (int f = 0; f < 4; ++f)
                        acc[f] = __builtin_amdgcn_mfma_f32_16x16x32_f16(As[f + dc], B0, acc[f], 0, 0, 0);
                }
            }
        }
    }

    // ---- epilogue: lanes l15<2 hold valid oc; D row = d4 = q*4+j ----
    if (l15 < 2) {
        float* ob = out + (size_t)(n * 2 + l15) * VOL + (size_t)(d1 * 16 + d2) * 256;
#pragma unroll
        for (int f = 0; f < 4; ++f) {
            const int d3 = wv * 4 + f;
            *(f32x4*)(ob + d3 * 16 + q * 4) = acc[f];
        }
    }
}

extern "C" void kernel_launch(void* const* d_in, const int* in_sizes, int n_in,
                              void* d_out, int out_size, void* d_ws, size_t ws_size,
                              hipStream_t stream)
{
    (void)in_sizes; (void)n_in; (void)out_size; (void)ws_size;
    const float* x      = (const float*)d_in[0];
    const float* k0     = (const float*)d_in[1];
    const float* k1     = (const float*)d_in[2];
    const float* k2     = (const float*)d_in[3];
    const float* k3     = (const float*)d_in[4];
    const float* k4     = (const float*)d_in[5];
    const float* k5     = (const float*)d_in[6];
    const float* slopes = (const float*)d_in[7];
    float* outp = (float*)d_out;

    // fp16 activation ping-pong buffers in d_ws: 33.5 MB each; wp5 after.
    u16* b0 = (u16*)d_ws;
    u16* b1 = b0 + (size_t)2048 * 8192;
    u16* wp5 = b1 + (size_t)2048 * 8192;    // 81*512 u16 = 83 KB

    // Hidden/layer0 weights in d_out (consumed before conv4d_out writes it):
    u16* wpk = (u16*)d_out;                 // 4*81*1024 u16 = 663 KB
    float* wp0 = outp + 165888;             // 5184 fp32 after that

    pack_h1<<<dim3(1296), 256, 0, stream>>>(k1, k2, k3, k4, wpk);
    pack_w0<<<dim3(21), 256, 0, stream>>>(k0, wp0);
    pack_k5<<<dim3(162), 256, 0, stream>>>(k5, wp5);

    const dim3 grid(8 * L * L);
    const dim3 block(256);

    conv4d_c2<<<grid, block, 0, stream>>>(x, wp0, slopes, b0);
    conv4d_mfma<<<grid, block, 0, stream>>>(b0, wpk + (size_t)0 * 81 * 1024, slopes, 1, b1);
    conv4d_mfma<<<grid, block, 0, stream>>>(b1, wpk + (size_t)1 * 81 * 1024, slopes, 2, b0);
    conv4d_mfma<<<grid, block, 0, stream>>>(b0, wpk + (size_t)2 * 81 * 1024, slopes, 3, b1);
    conv4d_mfma<<<grid, block, 0, stream>>>(b1, wpk + (size_t)3 * 81 * 1024, slopes, 4, b0);
    conv4d_out<<<grid, block, 0, stream>>>(b0, wp5, outp);
}

// Round 18
// 455.194 us; speedup vs baseline: 2.4024x; 1.0729x over previous
//
#include <hip/hip_runtime.h>
#include <cstddef>

#define L 16
#define PLANE 256
#define VOL 65536

typedef __attribute__((ext_vector_type(8))) short short8;
typedef __attribute__((ext_vector_type(8))) _Float16 half8;
typedef __attribute__((ext_vector_type(4))) float f32x4;
typedef __attribute__((ext_vector_type(4))) int i32x4;
typedef unsigned int u32;
typedef unsigned short u16;

__device__ __forceinline__ u16 f2h_bits(float f) {
    _Float16 h = (_Float16)f;             // RTN
    return __builtin_bit_cast(u16, h);
}

// DPP lane-shift within 16-lane rows; bound_ctrl + old=0 -> zero fill at row
// edges == SAME-padding for the d4 dimension, for free.
template <int CTRL>
__device__ __forceinline__ int dppmov(int v) {
    return __builtin_amdgcn_update_dpp(0, v, CTRL, 0xf, 0xf, true);
}
template <int CTRL>
__device__ __forceinline__ half8 dpp8(half8 v) {
    i32x4 u = __builtin_bit_cast(i32x4, v), r;
    r[0] = dppmov<CTRL>(u[0]); r[1] = dppmov<CTRL>(u[1]);
    r[2] = dppmov<CTRL>(u[2]); r[3] = dppmov<CTRL>(u[3]);
    return __builtin_bit_cast(half8, r);
}

// Async global->LDS, 16B per lane: LDS dest = uniform base + lane*16.
__device__ __forceinline__ void gload_lds16(const u16* g, u16* l) {
    __builtin_amdgcn_global_load_lds(
        (const __attribute__((address_space(1))) void*)g,
        (__attribute__((address_space(3))) void*)l, 16, 0, 0);
}

// ---------------------------------------------------------------------------
// Pack layer0 (IC=2) weights to fp32 [i][tap][o].
// ---------------------------------------------------------------------------
__global__ void pack_w0(const float* __restrict__ k0, float* __restrict__ dst)
{
    int idx = blockIdx.x * 256 + threadIdx.x;   // (i*81 + t)*32 + o
    if (idx >= 2 * 81 * 32) return;
    int o = idx & 31;
    int t = (idx >> 5) % 81;
    int i = idx / (32 * 81);
    dst[idx] = k0[(size_t)(o * 2 + i) * 81 + t];
}

// ---------------------------------------------------------------------------
// Pack k1..k4 to SINGLE fp16: wpk[layer][tap][o][i], 81*1024 u16 per layer.
// (R11: fp16 RTN on hidden weights moved absmax by exactly zero.)
// ---------------------------------------------------------------------------
__global__ void pack_h1(const float* __restrict__ k1, const float* __restrict__ k2,
                        const float* __restrict__ k3, const float* __restrict__ k4,
                        u16* __restrict__ dst)
{
    int idx = blockIdx.x * 256 + threadIdx.x;
    if (idx >= 4 * 81 * 1024) return;
    int layer = idx / (81 * 1024);
    int r = idx % (81 * 1024);
    int t = r / 1024;
    int oi = r % 1024;                  // o*32 + i
    int o = oi >> 5, i = oi & 31;
    const float* src = layer == 0 ? k1 : layer == 1 ? k2 : layer == 2 ? k3 : k4;
    float w = src[(size_t)(o * 32 + i) * 81 + t];
    dst[((size_t)layer * 81 + t) * 1024 + oi] = f2h_bits(w);
}

// ---------------------------------------------------------------------------
// Pack k5 (OC=2) to fp16 padded to 16: wp5[tap][n=16][k=32], 81*512 u16.
// ---------------------------------------------------------------------------
__global__ void pack_k5(const float* __restrict__ k5, u16* __restrict__ dst)
{
    int idx = blockIdx.x * 256 + threadIdx.x;   // t*512 + o*32 + i
    if (idx >= 81 * 512) return;
    int t = idx >> 9;
    int oi = idx & 511;
    int o = oi >> 5, i = oi & 31;
    float w = (o < 2) ? k5[(size_t)(o * 32 + i) * 81 + t] : 0.0f;
    dst[idx] = f2h_bits(w);
}

// ---------------------------------------------------------------------------
// MFMA conv layer, IC=OC=32, PReLU. fp16 single-pass. A path: no-LDS,
// direct global b128 + DPP shifts. B path: per-plane 18 KB staged into a
// 2x18KB LDS double-buffer via async global_load_lds (R17-proven: fixes
// B-stream L1 thrash; 612->488 µs total).
// ---------------------------------------------------------------------------
__global__ __launch_bounds__(256, 3)
void conv4d_mfma(const u16* __restrict__ xh, const u16* __restrict__ wl_,
                 const float* __restrict__ slopes, int sidx, u16* __restrict__ yh)
{
    const int blk = blockIdx.x;
    // XCD swizzle: xcd = blk&7 owns d1 rows {2*xcd, 2*xcd+1}, n-major order.
    const int xcd = blk & 7;
    const int s = blk >> 3;
    const int n = s >> 5;
    const int t_ = s & 31;
    const int d1 = xcd * 2 + (t_ >> 4);
    const int d2 = t_ & 15;

    const int lane = threadIdx.x & 63, wv = threadIdx.x >> 6;
    const int l15 = lane & 15, q = lane >> 4;

    __shared__ __attribute__((aligned(16))) u16 bs[2][9216];   // 2 x 18 KB

    f32x4 acc[4][2];
#pragma unroll
    for (int f = 0; f < 4; ++f)
#pragma unroll
        for (int nf = 0; nf < 2; ++nf)
            acc[f][nf] = (f32x4){0.f, 0.f, 0.f, 0.f};

    const size_t nbase = (size_t)n * 256 * 8192;
    const int aoff = l15 * 32 + q * 8;       // within-plane frag offset (dd=1)
    const half8 zero8 = (half8)(_Float16)0;

    // Stage plane p's 9 taps (18 KB, contiguous at wl_ + p*9216) into
    // bs[p&1]. 18 chunks of 1 KB; wave wv takes chunks c ≡ wv (mod 4).
    auto stageB = [&](int p) {
        const u16* src = wl_ + (size_t)p * 9216;
        u16* dst = &bs[p & 1][0];
        for (int c = wv; c < 18; c += 4)
            gload_lds16(src + c * 512 + lane * 8, dst + c * 512);
    };

    stageB(0);

#pragma unroll 1
    for (int p = 0; p < 9; ++p) {
        __syncthreads();                 // publishes bs[p&1] (drains stage p)
        if (p < 8) stageB(p + 1);        // async, lands during compute below

        const int da = p / 3, db = p % 3;
        const int a = d1 + da - 1;
        const int b = d2 + db - 1;
        if ((unsigned)a > 15u || (unsigned)b > 15u) continue;  // pad plane = 0

        const u16* Hp = xh + nbase + (size_t)(a * 16 + b) * 8192;
        const u16* wt0 = &bs[p & 1][0];

        // base A-frags (dd=1, col=l15): rows wv*4-1 .. wv*4+4
        half8 ax[6];
#pragma unroll
        for (int r6 = 0; r6 < 6; ++r6) {
            const int d3c = (wv * 4 + r6 - 1) & 15;   // wrap; edges zeroed
            ax[r6] = *(const half8*)(Hp + d3c * 512 + aoff);
        }
        if (wv == 0)      ax[0] = zero8;  // d3 = -1 pad row
        else if (wv == 3) ax[5] = zero8;  // d3 = 16 pad row

        // ---- dd outer: shift A once, 3 dc taps reuse it; B from LDS ----
#pragma unroll
        for (int dd = 0; dd < 3; ++dd) {
            half8 As[6];
#pragma unroll
            for (int r6 = 0; r6 < 6; ++r6) {
                if (dd == 0)      As[r6] = dpp8<0x111>(ax[r6]); // col-1
                else if (dd == 1) As[r6] = ax[r6];
                else              As[r6] = dpp8<0x101>(ax[r6]); // col+1
            }
#pragma unroll
            for (int dc = 0; dc < 3; ++dc) {
                const u16* wb = wt0 + (dc * 3 + dd) * 1024;
                half8 B0 = *(const half8*)(wb + aoff);
                half8 B1 = *(const half8*)(wb + 512 + aoff);
#pragma unroll
                for (int f = 0; f < 4; ++f) {
                    acc[f][0] = __builtin_amdgcn_mfma_f32_16x16x32_f16(As[f + dc], B0, acc[f][0], 0, 0, 0);
                    acc[f][1] = __builtin_amdgcn_mfma_f32_16x16x32_f16(As[f + dc], B1, acc[f][1], 0, 0, 0);
                }
            }
        }
    }

    // ---- epilogue: PReLU, fp16 pack, store to [pos][ch] buffer ----
    const float slope = slopes[sidx];
    u16* Hb = yh + ((size_t)(n * 256) + d1 * 16 + d2) * 8192;
#pragma unroll
    for (int f = 0; f < 4; ++f) {
#pragma unroll
        for (int nf = 0; nf < 2; ++nf) {
            const int o = nf * 16 + l15;
#pragma unroll
            for (int j = 0; j < 4; ++j) {
                float v = acc[f][nf][j];
                v = v >= 0.f ? v : slope * v;
                const int pos = (wv * 4 + f) * 16 + q * 4 + j;
                Hb[pos * 32 + o] = f2h_bits(v);
            }
        }
    }
}

// ---------------------------------------------------------------------------
// Layer 0: IC=2, fp32 math, PReLU; original x layout in, fp16 out.
// ---------------------------------------------------------------------------
__global__ __launch_bounds__(256, 4)
void conv4d_c2(const float* __restrict__ x, const float* __restrict__ wp,
               const float* __restrict__ slopes, u16* __restrict__ yh)
{
    const int blk = blockIdx.x;
    const int d2 = blk & 15, d1 = (blk >> 4) & 15, n = blk >> 8;
    const int tid = threadIdx.x;
    const int c = tid >> 4, d = tid & 15;

    __shared__ float xs[3][3][18][18];
    float* xsf = &xs[0][0][0][0];
    for (int idx = tid; idx < 3 * 3 * 18 * 18; idx += 256) xsf[idx] = 0.0f;

    float acc[32];
#pragma unroll
    for (int o = 0; o < 32; ++o) acc[o] = 0.0f;

    for (int i = 0; i < 2; ++i) {
#pragma unroll
        for (int da = 0; da < 3; ++da) {
            const int a = d1 + da - 1;
#pragma unroll
            for (int db = 0; db < 3; ++db) {
                const int b = d2 + db - 1;
                float v = 0.0f;
                if (a >= 0 && a < L && b >= 0 && b < L)
                    v = x[(((size_t)(n * 2 + i) * L + a) * L + b) * PLANE + c * L + d];
                xs[da][db][c + 1][d + 1] = v;
            }
        }
        __syncthreads();

        const float* wpi = wp + (size_t)i * 81 * 32;
#pragma unroll 1
        for (int da = 0; da < 3; ++da) {
#pragma unroll 1
            for (int db = 0; db < 3; ++db) {
                float xv[3][3];
#pragma unroll
                for (int dc = 0; dc < 3; ++dc)
#pragma unroll
                    for (int dd = 0; dd < 3; ++dd)
                        xv[dc][dd] = xs[da][db][c + dc][d + dd];

                const float* wt = wpi + (da * 3 + db) * 9 * 32;
#pragma unroll
                for (int dc = 0; dc < 3; ++dc) {
#pragma unroll
                    for (int dd = 0; dd < 3; ++dd) {
                        const float* wr = wt + (dc * 3 + dd) * 32;
#pragma unroll
                        for (int o = 0; o < 32; ++o)
                            acc[o] = fmaf(xv[dc][dd], wr[o], acc[o]);
                    }
                }
            }
        }
        __syncthreads();
    }

    const float slope = slopes[0];
    u16* Hb = yh + ((size_t)(n * 256) + d1 * 16 + d2) * 8192 + (size_t)tid * 32;
    short8 hs[4];
#pragma unroll
    for (int k = 0; k < 4; ++k)
#pragma unroll
        for (int j = 0; j < 8; ++j) {
            float v = acc[k * 8 + j];
            v = v >= 0.f ? v : slope * v;
            hs[k][j] = (short)f2h_bits(v);
        }
#pragma unroll
    for (int k = 0; k < 4; ++k)
        *(short8*)(Hb + k * 8) = hs[k];
}

// ---------------------------------------------------------------------------
// Final layer: IC=32, OC=2 (padded to 16), no PReLU. MFMA; R18: B staged
// per-plane (9 taps = 9 KB contiguous) into 2x9KB LDS double-buffer via
// async global_load_lds — same fix as the hidden layers (81 KB B-stream
// thrashed L1; in-loop B loads were L2-latency on the dependent path).
// ---------------------------------------------------------------------------
__global__ __launch_bounds__(256, 4)
void conv4d_out(const u16* __restrict__ xh, const u16* __restrict__ w5,
                float* __restrict__ out)
{
    const int blk = blockIdx.x;
    const int xcd = blk & 7;      // same swizzle as hidden layers (L2 locality)
    const int s = blk >> 3;
    const int n = s >> 5;
    const int t_ = s & 31;
    const int d1 = xcd * 2 + (t_ >> 4);
    const int d2 = t_ & 15;

    const int lane = threadIdx.x & 63, wv = threadIdx.x >> 6;
    const int l15 = lane & 15, q = lane >> 4;

    __shared__ __attribute__((aligned(16))) u16 bs[2][4608];   // 2 x 9 KB

    f32x4 acc[4];
#pragma unroll
    for (int f = 0; f < 4; ++f) acc[f] = (f32x4){0.f, 0.f, 0.f, 0.f};

    const size_t nbase = (size_t)n * 256 * 8192;
    const int aoff = l15 * 32 + q * 8;
    const half8 zero8 = (half8)(_Float16)0;
    const int boff = l15 * 32 + q * 8;    // B[n=l15][k=q*8..], 512 u16/tap

    // Stage plane p's 9 taps (9 KB, contiguous at w5 + p*4608) into bs[p&1].
    // 9 chunks of 1 KB; wave wv takes chunks c ≡ wv (mod 4).
    auto stageB = [&](int p) {
        const u16* src = w5 + (size_t)p * 4608;
        u16* dst = &bs[p & 1][0];
        for (int c = wv; c < 9; c += 4)
            gload_lds16(src + c * 512 + lane * 8, dst + c * 512);
    };

    stageB(0);

#pragma unroll 1
    for (int p = 0; p < 9; ++p) {
        __syncthreads();                 // publishes bs[p&1]
        if (p < 8) stageB(p + 1);        // async, lands during compute below

        const int da = p / 3, db = p % 3;
        const int a = d1 + da - 1;
        const int b = d2 + db - 1;
        if ((unsigned)a > 15u || (unsigned)b > 15u) continue;

        const u16* Hp = xh + nbase + (size_t)(a * 16 + b) * 8192;
        const u16* wt0 = &bs[p & 1][0];

        half8 ax[6];
#pragma unroll
        for (int r6 = 0; r6 < 6; ++r6) {
            const int d3c = (wv * 4 + r6 - 1) & 15;
            ax[r6] = *(const half8*)(Hp + d3c * 512 + aoff);
        }
        if (wv == 0)      ax[0] = zero8;
        else if (wv == 3) ax[5] = zero8;

#pragma unroll
        for (int dd = 0; dd < 3; ++dd) {
            half8 As[6];
#pragma unroll
            for (int r6 = 0; r6 < 6; ++r6) {
                if (dd == 0)      As[r6] = dpp8<0x111>(ax[r6]);
                else if (dd == 1) As[r6] = ax[r6];
                else              As[r6] = dpp8<0x101>(ax[r6]);
            }
#pragma unroll
            for (int dc = 0; dc < 3; ++dc) {
                const u16* wb = wt0 + (dc * 3 + dd) * 512;
                half8 B0 = *(const half8*)(wb + boff);
#pragma unroll
                for (int f = 0; f < 4; ++f)
                    acc[f] = __builtin_amdgcn_mfma_f32_16x16x32_f16(As[f + dc], B0, acc[f], 0, 0, 0);
            }
        }
    }

    // ---- epilogue: lanes l15<2 hold valid oc; D row = d4 = q*4+j ----
    if (l15 < 2) {
        float* ob = out + (size_t)(n * 2 + l15) * VOL + (size_t)(d1 * 16 + d2) * 256;
#pragma unroll
        for (int f = 0; f < 4; ++f) {
            const int d3 = wv * 4 + f;
            *(f32x4*)(ob + d3 * 16 + q * 4) = acc[f];
        }
    }
}

extern "C" void kernel_launch(void* const* d_in, const int* in_sizes, int n_in,
                              void* d_out, int out_size, void* d_ws, size_t ws_size,
                              hipStream_t stream)
{
    (void)in_sizes; (void)n_in; (void)out_size; (void)ws_size;
    const float* x      = (const float*)d_in[0];
    const float* k0     = (const float*)d_in[1];
    const float* k1     = (const float*)d_in[2];
    const float* k2     = (const float*)d_in[3];
    const float* k3     = (const float*)d_in[4];
    const float* k4     = (const float*)d_in[5];
    const float* k5     = (const float*)d_in[6];
    const float* slopes = (const float*)d_in[7];
    float* outp = (float*)d_out;

    // fp16 activation ping-pong buffers in d_ws: 33.5 MB each; wp5 after.
    u16* b0 = (u16*)d_ws;
    u16* b1 = b0 + (size_t)2048 * 8192;
    u16* wp5 = b1 + (size_t)2048 * 8192;    // 81*512 u16 = 83 KB

    // Hidden/layer0 weights in d_out (consumed before conv4d_out writes it):
    u16* wpk = (u16*)d_out;                 // 4*81*1024 u16 = 663 KB
    float* wp0 = outp + 165888;             // 5184 fp32 after that

    pack_h1<<<dim3(1296), 256, 0, stream>>>(k1, k2, k3, k4, wpk);
    pack_w0<<<dim3(21), 256, 0, stream>>>(k0, wp0);
    pack_k5<<<dim3(162), 256, 0, stream>>>(k5, wp5);

    const dim3 grid(8 * L * L);
    const dim3 block(256);

    conv4d_c2<<<grid, block, 0, stream>>>(x, wp0, slopes, b0);
    conv4d_mfma<<<grid, block, 0, stream>>>(b0, wpk + (size_t)0 * 81 * 1024, slopes, 1, b1);
    conv4d_mfma<<<grid, block, 0, stream>>>(b1, wpk + (size_t)1 * 81 * 1024, slopes, 2, b0);
    conv4d_mfma<<<grid, block, 0, stream>>>(b0, wpk + (size_t)2 * 81 * 1024, slopes, 3, b1);
    conv4d_mfma<<<grid, block, 0, stream>>>(b1, wpk + (size_t)3 * 81 * 1024, slopes, 4, b0);
    conv4d_out<<<grid, block, 0, stream>>>(b0, wp5, outp);
}